// Round 2
// baseline (113.766 us; speedup 1.0000x reference)
//
#include <hip/hip_runtime.h>
#include <math.h>

#define W 512
#define H 512
#define NUM_R 725
#define NUM_T 180
#define RCHUNK 64    // n-samples per block (gridDim.y = 512/64 = 8)
#define ROWS 16      // rows staged in LDS per barrier pair (16*512*4B = 32 KB)

// ---------------------------------------------------------------------------
// Transpose 512x512 f32: imgT[n*W + x] = img[x*W + n]
// ---------------------------------------------------------------------------
__global__ __launch_bounds__(256) void transpose_k(const float* __restrict__ in,
                                                   float* __restrict__ out) {
    __shared__ float tile[32][33];
    const int bx = blockIdx.x * 32, by = blockIdx.y * 32;
    const int tx = threadIdx.x, ty = threadIdx.y;  // block (32, 8)
#pragma unroll
    for (int j = 0; j < 32; j += 8)
        tile[ty + j][tx] = in[(size_t)(by + ty + j) * W + (bx + tx)];
    __syncthreads();
#pragma unroll
    for (int j = 0; j < 32; j += 8)
        out[(size_t)(bx + ty + j) * H + (by + tx)] = tile[tx][ty + j];
}

// ---------------------------------------------------------------------------
// Hough accumulation, Q40 fixed-point incremental sampling.
// y_f(n) = rho*inv + n*nk2 is an arithmetic progression; quantize once to
// 64-bit Q40 and advance by exact integer adds. y = (Yq + 2^39) >> 40 is
// round-half-up of the quantized value (quant err <= ~2.5e-10; ties measure-0).
// ---------------------------------------------------------------------------
__global__ __launch_bounds__(256) void hough_k(const float* __restrict__ img,
                                               const float* __restrict__ imgT,
                                               float* __restrict__ out,
                                               int hasT) {
    const int t   = blockIdx.x;            // theta index 0..179
    const int n0  = blockIdx.y * RCHUNK;   // n-chunk base
    const int tid = threadIdx.x;

    __shared__ float lds[ROWS * W];

    // ---- per-theta constants (f64, mirroring numpy; identical to R1) ----
    const double theta = (double)t * (M_PI / 180.0);
    const double s = sin(theta);
    const double c = cos(theta);
    const bool use_x = fabs(s) >= fabs(c);
    double dd = use_x ? s : c;             // divisor (|dd| >= 0.707, guard moot)
    if (fabs(dd) < 1e-6) dd = 1.0;
    const double a   = use_x ? c : s;
    const double inv = 1.0 / dd;
    const double nk2 = -(a * inv);

    const double diag = sqrt(524288.0);          // sqrt(W*W + H*H) in f64
    const double step = (2.0 * diag) / 724.0;    // np.linspace step

    const int r1 = tid, r2 = tid + 256, r3 = tid + 512;
    const int r3c = (r3 < NUM_R) ? r3 : (NUM_R - 1);
    double rho1 = (double)r1 * step - diag;
    double rho2 = (double)r2 * step - diag;
    double rho3 = (double)r3c * step - diag;
    if (r1 == NUM_R - 1) rho1 = diag;
    if (r2 == NUM_R - 1) rho2 = diag;
    if (r3c == NUM_R - 1) rho3 = diag;

    // ---- Q40 fixed-point state ----
    const double SCALE = 1099511627776.0;  // 2^40
    const long long NK2q = (long long)rint(nk2 * SCALE);
    const long long HALF = 1ll << 39;
    const long long base0 = (long long)n0 * NK2q + HALF;
    long long Y1 = (long long)rint(rho1 * inv * SCALE) + base0;
    long long Y2 = (long long)rint(rho2 * inv * SCALE) + base0;
    long long Y3 = (long long)rint(rho3 * inv * SCALE) + base0;

    const float* base = use_x ? img : imgT;

    float acc1 = 0.f, acc2 = 0.f, acc3 = 0.f;

    for (int j0 = 0; j0 < RCHUNK; j0 += ROWS) {
        const int nbase = n0 + j0;
        // ---- stage ROWS rows into LDS ----
        if (use_x || hasT) {
            const float4* src = (const float4*)(base + (size_t)nbase * W);
            float4* dst = (float4*)lds;
#pragma unroll
            for (int i = 0; i < (ROWS * W / 4) / 256; ++i)
                dst[tid + i * 256] = src[tid + i * 256];
        } else {
            // fallback (no workspace): strided column loads
            for (int i = tid; i < ROWS * W; i += 256) {
                const int j = i >> 9;
                const int x = i & (W - 1);
                lds[i] = img[(size_t)x * W + (nbase + j)];
            }
        }
        __syncthreads();

#pragma unroll
        for (int j = 0; j < ROWS; ++j) {
            const int y1 = (int)(Y1 >> 40);  Y1 += NK2q;
            const int y2 = (int)(Y2 >> 40);  Y2 += NK2q;
            const int y3 = (int)(Y3 >> 40);  Y3 += NK2q;
            const float* row = lds + j * W;
            const float v1 = row[min(max(y1, 0), W - 1)];
            const float v2 = row[min(max(y2, 0), W - 1)];
            const float v3 = row[min(max(y3, 0), W - 1)];
            acc1 += ((unsigned)y1 < (unsigned)W) ? v1 : 0.f;
            acc2 += ((unsigned)y2 < (unsigned)W) ? v2 : 0.f;
            acc3 += ((unsigned)y3 < (unsigned)W) ? v3 : 0.f;
        }
        __syncthreads();
    }

    atomicAdd(&out[(size_t)r1 * NUM_T + t], acc1);
    atomicAdd(&out[(size_t)r2 * NUM_T + t], acc2);
    if (r3 < NUM_R) atomicAdd(&out[(size_t)r3 * NUM_T + t], acc3);
}

extern "C" void kernel_launch(void* const* d_in, const int* in_sizes, int n_in,
                              void* d_out, int out_size, void* d_ws, size_t ws_size,
                              hipStream_t stream) {
    const float* img = (const float*)d_in[0];
    float* out = (float*)d_out;

    // d_out is poisoned before every timed call; zero it (atomic accumulation).
    hipMemsetAsync(d_out, 0, (size_t)NUM_R * NUM_T * sizeof(float), stream);

    const int hasT = (ws_size >= (size_t)W * H * sizeof(float)) ? 1 : 0;
    float* imgT = (float*)d_ws;
    if (hasT) {
        transpose_k<<<dim3(16, 16), dim3(32, 8), 0, stream>>>(img, imgT);
    }

    hough_k<<<dim3(NUM_T, W / RCHUNK), dim3(256), 0, stream>>>(
        img, hasT ? imgT : img, out, hasT);
}

// Round 3
// 85.599 us; speedup vs baseline: 1.3291x; 1.3291x over previous
//
#include <hip/hip_runtime.h>
#include <math.h>

#define W 512
#define H 512
#define NUM_R 725
#define NUM_T 180

// ---------------------------------------------------------------------------
// Transpose 512x512 f32: imgT[n*W + x] = img[x*W + n]
// ---------------------------------------------------------------------------
__global__ __launch_bounds__(256) void transpose_k(const float* __restrict__ in,
                                                   float* __restrict__ out) {
    __shared__ float tile[32][33];
    const int bx = blockIdx.x * 32, by = blockIdx.y * 32;
    const int tx = threadIdx.x, ty = threadIdx.y;  // block (32, 8)
#pragma unroll
    for (int j = 0; j < 32; j += 8)
        tile[ty + j][tx] = in[(size_t)(by + ty + j) * W + (bx + tx)];
    __syncthreads();
#pragma unroll
    for (int j = 0; j < 32; j += 8)
        out[(size_t)(bx + ty + j) * H + (by + tx)] = tile[tx][ty + j];
}

// ---------------------------------------------------------------------------
// Pure-gather Hough: one thread per (r, t). No LDS, no barriers, no atomics.
// Image (1 MB) is L2-resident; lanes = consecutive r so each wave's gather
// spans ~11 cache lines of one row. y-sweep thetas read the transposed image
// so both sweeps walk row-contiguous data.
// Q40 fixed-point incremental y (validated R2: absmax 2.0 vs np reference).
// ---------------------------------------------------------------------------
__global__ __launch_bounds__(256) void hough_k(const float* __restrict__ img,
                                               const float* __restrict__ imgT,
                                               float* __restrict__ out,
                                               int hasT) {
    const int t = blockIdx.x;                       // theta index 0..179
    const int r = blockIdx.y * 256 + threadIdx.x;   // rho index 0..767
    const int rc = (r < NUM_R) ? r : (NUM_R - 1);

    // ---- per-theta constants (f64, mirroring numpy) ----
    const double theta = (double)t * (M_PI / 180.0);
    const double s = sin(theta);
    const double c = cos(theta);
    const bool use_x = fabs(s) >= fabs(c);
    double dd = use_x ? s : c;
    if (fabs(dd) < 1e-6) dd = 1.0;
    const double a   = use_x ? c : s;
    const double inv = 1.0 / dd;
    const double nk2 = -(a * inv);

    const double diag = sqrt(524288.0);           // sqrt(W*W + H*H)
    const double step = (2.0 * diag) / 724.0;     // np.linspace step
    double rho = (double)rc * step - diag;
    if (rc == NUM_R - 1) rho = diag;

    // ---- Q40 fixed-point state ----
    const double SCALE = 1099511627776.0;         // 2^40
    const long long NK2q = (long long)rint(nk2 * SCALE);
    long long Y = (long long)rint(rho * inv * SCALE) + (1ll << 39);

    float acc = 0.f;

    if (use_x || hasT) {
        const float* __restrict__ base = use_x ? img : imgT;
#pragma unroll 8
        for (int n = 0; n < W; ++n) {
            const int y = (int)(Y >> 40);
            Y += NK2q;
            const int yc = min(max(y, 0), W - 1);
            const float v = base[n * W + yc];
            acc += ((unsigned)y < (unsigned)W) ? v : 0.f;
        }
    } else {
        // fallback (no workspace for transpose): column walk, uncoalesced
#pragma unroll 4
        for (int n = 0; n < W; ++n) {
            const int y = (int)(Y >> 40);
            Y += NK2q;
            const int yc = min(max(y, 0), W - 1);
            const float v = img[yc * W + n];
            acc += ((unsigned)y < (unsigned)W) ? v : 0.f;
        }
    }

    if (r < NUM_R) out[(size_t)r * NUM_T + t] = acc;
}

extern "C" void kernel_launch(void* const* d_in, const int* in_sizes, int n_in,
                              void* d_out, int out_size, void* d_ws, size_t ws_size,
                              hipStream_t stream) {
    const float* img = (const float*)d_in[0];
    float* out = (float*)d_out;

    const int hasT = (ws_size >= (size_t)W * H * sizeof(float)) ? 1 : 0;
    float* imgT = (float*)d_ws;
    if (hasT) {
        transpose_k<<<dim3(16, 16), dim3(32, 8), 0, stream>>>(img, imgT);
    }

    // grid: 180 thetas x 3 r-tiles of 256 (covers 725 rho bins)
    hough_k<<<dim3(NUM_T, (NUM_R + 255) / 256), dim3(256), 0, stream>>>(
        img, hasT ? imgT : img, out, hasT);
}